// Round 1
// 1673.863 us; speedup vs baseline: 1.0720x; 1.0720x over previous
//
#include <hip/hip_runtime.h>

// Problem constants
constexpr int HD = 4096;   // hidden dim
constexpr int TD = 8192;   // tokens

typedef __bf16 bf16;
typedef __bf16 bf16x4 __attribute__((ext_vector_type(4)));
typedef __bf16 bf16x8 __attribute__((ext_vector_type(8)));
typedef float  f32x4  __attribute__((ext_vector_type(4)));

// ---------------------------------------------------------------------------
// fp8 e4m3fn round-to-nearest-even of a non-negative value already clipped to
// [0, 448].  ulp = 2^(e-3) for normals (e >= -6), 2^-9 for subnormals.
__device__ __forceinline__ float e4m3_round(float v) {
    if (!(v > 0.0f)) return 0.0f;
    unsigned b = __float_as_uint(v);
    int exp = (int)((b >> 23) & 255) - 127;
    int shift = (exp < -6) ? -9 : (exp - 3);          // shift in [-9, 5]
    float sc  = __uint_as_float((unsigned)(127 + shift) << 23);  // 2^shift
    float isc = __uint_as_float((unsigned)(127 - shift) << 23);  // 2^-shift
    return rintf(v * isc) * sc;                        // RNE on the grid
}

// fp4 e2m1 round-to-nearest, ties away from zero (matches jnp searchsorted
// side='right' on midpoints [.25,.75,1.25,1.75,2.5,3.5,5.0]).
__device__ __forceinline__ float fp4_round(float x) {
    float s = (x < 0.0f) ? -1.0f : 1.0f;
    float a = fminf(fabsf(x), 6.0f);
    float v;
    if      (a < 0.25f) v = 0.0f;
    else if (a < 0.75f) v = 0.5f;
    else if (a < 1.25f) v = 1.0f;
    else if (a < 1.75f) v = 1.5f;
    else if (a < 2.5f)  v = 2.0f;
    else if (a < 3.5f)  v = 3.0f;
    else if (a < 5.0f)  v = 4.0f;
    else                v = 6.0f;
    return s * v;
}

// async global->LDS, 16 bytes per lane; LDS dest must be wave-uniform base.
__device__ __forceinline__ void load_lds16(const void* g, void* l) {
    typedef __attribute__((address_space(1))) const void gv_t;
    typedef __attribute__((address_space(3))) void lv_t;
    __builtin_amdgcn_global_load_lds((gv_t*)g, (lv_t*)l, 16, 0, 0);
}

// ---------------------------------------------------------------------------
// Weight quant+dequant: w[3][H][H] fp32 -> Bdeq[3][H][H] bf16 (= q*sc exactly).
// One thread per float4; 4 consecutive lanes form one 16-elem quant block.
__global__ __launch_bounds__(256) void quant_w_kernel(
        const float* __restrict__ w, const float* __restrict__ wg,
        bf16* __restrict__ bdeq) {
    const size_t t4 = (size_t)blockIdx.x * 256 + threadIdx.x;   // float4 index
    const int mat = (int)(t4 >> 22);                            // / (H*H/4)
    const float gs = wg[mat];
    const float4 v = ((const float4*)w)[t4];
    float am = fmaxf(fmaxf(fabsf(v.x), fabsf(v.y)), fmaxf(fabsf(v.z), fabsf(v.w)));
    am = fmaxf(am, __shfl_xor(am, 1));
    am = fmaxf(am, __shfl_xor(am, 2));
    const float sc = e4m3_round(fminf((am / 6.0f) * gs, 448.0f));
    bf16x4 o;
    if (sc > 0.0f) {
        o[0] = (bf16)(fp4_round(v.x * gs / sc) * sc);
        o[1] = (bf16)(fp4_round(v.y * gs / sc) * sc);
        o[2] = (bf16)(fp4_round(v.z * gs / sc) * sc);
        o[3] = (bf16)(fp4_round(v.w * gs / sc) * sc);
    } else {
        o[0] = o[1] = o[2] = o[3] = (bf16)0.0f;
    }
    ((bf16x4*)bdeq)[t4] = o;
}

// ---------------------------------------------------------------------------
// Fused (relu) + rmsnorm + activation quant-dequant.
// mode 0: in=hidden, relu, write resid_out(fp32), quant -> qout(bf16)
// mode 1: in=x,      quant -> qout(bf16)
// mode 2: in=x,      write y(fp32) -> yout (final output; in-place safe)
__global__ __launch_bounds__(256) void rms_quant_kernel(
        const float* __restrict__ in, float* __restrict__ resid_out,
        const float* __restrict__ nw, const float* __restrict__ gsp,
        bf16* __restrict__ qout, float* __restrict__ yout, const int mode) {
    const int row  = blockIdx.x;
    const int tid  = threadIdx.x;
    const int lane = tid & 63;
    const int wave = tid >> 6;
    const float* x = in + (size_t)row * HD;

    float4 v[4];
    float ss = 0.0f;
#pragma unroll
    for (int c = 0; c < 4; c++) {
        v[c] = ((const float4*)x)[c * 256 + tid];
        if (mode == 0) {
            v[c].x = fmaxf(v[c].x, 0.0f);
            v[c].y = fmaxf(v[c].y, 0.0f);
            v[c].z = fmaxf(v[c].z, 0.0f);
            v[c].w = fmaxf(v[c].w, 0.0f);
        }
        ss += v[c].x * v[c].x + v[c].y * v[c].y + v[c].z * v[c].z + v[c].w * v[c].w;
    }
    if (mode == 0) {
        float4* r = (float4*)(resid_out + (size_t)row * HD);
#pragma unroll
        for (int c = 0; c < 4; c++) r[c * 256 + tid] = v[c];
    }
#pragma unroll
    for (int m = 1; m < 64; m <<= 1) ss += __shfl_xor(ss, m);
    __shared__ float sred[4];
    if (lane == 0) sred[wave] = ss;
    __syncthreads();
    const float total = sred[0] + sred[1] + sred[2] + sred[3];
    const float rs = rsqrtf(total * (1.0f / HD) + 1e-6f);
    const float gs = (mode == 2) ? 0.0f : *gsp;

#pragma unroll
    for (int c = 0; c < 4; c++) {
        const float4 nv = ((const float4*)nw)[c * 256 + tid];
        float4 y;
        y.x = v[c].x * rs * nv.x;
        y.y = v[c].y * rs * nv.y;
        y.z = v[c].z * rs * nv.z;
        y.w = v[c].w * rs * nv.w;
        if (mode == 2) {
            ((float4*)(yout + (size_t)row * HD))[c * 256 + tid] = y;
        } else {
            float am = fmaxf(fmaxf(fabsf(y.x), fabsf(y.y)), fmaxf(fabsf(y.z), fabsf(y.w)));
            am = fmaxf(am, __shfl_xor(am, 1));
            am = fmaxf(am, __shfl_xor(am, 2));
            const float sc = e4m3_round(fminf((am / 6.0f) * gs, 448.0f));
            bf16x4 o;
            if (sc > 0.0f) {
                o[0] = (bf16)(fp4_round(y.x * gs / sc) * sc);
                o[1] = (bf16)(fp4_round(y.y * gs / sc) * sc);
                o[2] = (bf16)(fp4_round(y.z * gs / sc) * sc);
                o[3] = (bf16)(fp4_round(y.w * gs / sc) * sc);
            } else {
                o[0] = o[1] = o[2] = o[3] = (bf16)0.0f;
            }
            ((bf16x4*)(qout + (size_t)row * HD))[c * 256 + tid] = o;
        }
    }
}

// ---------------------------------------------------------------------------
// C[M,N] = (A[M,K] @ B[N,K]^T) * alpha + C   (in-place residual add)
//
// 256x256 tile, 8 waves (2M x 4N), BK=32 K-tiles in a 4-deep circular LDS
// pipeline (4 x 32 KB = 128 KB). Two phases per K-tile, each:
//   {stage 2 x global_load_lds  ||  4-8 x ds_read_b128}  -> s_barrier
//   -> setprio(1) -> 16 x mfma_f32_16x16x32_bf16 -> setprio(0) -> s_barrier
// Counted vmcnt (never 0 in main loop): per wave 4 load-insts/tile; the
// tile-boundary s_waitcnt vmcnt(8) leaves exactly tiles t+2,t+3 in flight and
// guarantees tile t+1 landed; the following s_barrier publishes it to all
// waves. LDS is XOR-swizzled: phys = logical ^ (((row>>1)&3)<<4) -- bank-
// balanced ds_read_b128 (2 lanes/slot, free). global_load_lds writes LINEAR
// LDS; the per-lane GLOBAL source address is pre-inverse-swizzled (involution).
__global__ __launch_bounds__(512, 2) void gemm_bt_kernel(
        const bf16* __restrict__ A, const bf16* __restrict__ B,
        float* __restrict__ C,
        const float* __restrict__ agp, const float* __restrict__ wgp) {
    __shared__ __align__(16) bf16 sA[4 * 8192];   // 4 x [256 rows][32 cols] bf16
    __shared__ __align__(16) bf16 sB[4 * 8192];

    constexpr int NT = HD / 32;          // 128 K-tiles

    const int tid  = threadIdx.x;        // 0..511
    const int wave = tid >> 6;
    const int lane = tid & 63;
    const int l16  = lane & 15;
    const int quad = lane >> 4;
    const int wr   = wave >> 2;          // 0..1  (M)
    const int wc   = wave & 3;           // 0..3  (N)

    // XCD-aware bijective swizzle: nwg=512, 8 XCDs, 64 blocks per XCD chunk.
    const int bid = blockIdx.x;
    const int swz = (bid & 7) * 64 + (bid >> 3);
    const int tileM = (swz & 31) * 256;  // 32 M-tiles (m-fastest: B-panel reuse in L2)
    const int tileN = (swz >> 5) * 256;  // 16 N-tiles

    const float alpha = 1.0f / ((*wgp) * (*agp));

    f32x4 acc[8][4];
#pragma unroll
    for (int mi = 0; mi < 8; ++mi)
#pragma unroll
        for (int ni = 0; ni < 4; ++ni)
            acc[mi][ni] = (f32x4){0.0f, 0.0f, 0.0f, 0.0f};

    // Staging: thread covers linear 16B chunks p0 = tid*16, p1 = 8192+tid*16
    // of each 16 KB tile buffer; global source = inverse-swizzle(p) decoded
    // as (row = q>>6, colE = (q&63)>>1) relative to (tile row, k0).
    const int p0 = tid * 16;
    const int p1 = 8192 + tid * 16;
    const int q0 = p0 ^ (((p0 >> 7) & 3) << 4);
    const int q1 = p1 ^ (((p1 >> 7) & 3) << 4);
    const bf16* gA0 = A + (size_t)(tileM + (q0 >> 6)) * HD + ((q0 & 63) >> 1);
    const bf16* gA1 = A + (size_t)(tileM + (q1 >> 6)) * HD + ((q1 & 63) >> 1);
    const bf16* gB0 = B + (size_t)(tileN + (q0 >> 6)) * HD + ((q0 & 63) >> 1);
    const bf16* gB1 = B + (size_t)(tileN + (q1 >> 6)) * HD + ((q1 & 63) >> 1);
    char* const lA = (char*)sA + wave * 1024;   // wave-uniform LDS bases
    char* const lB = (char*)sB + wave * 1024;

#define STAGE_A(b, k0) do {                                       \
        load_lds16(gA0 + (k0), lA + (b) * 16384);                 \
        load_lds16(gA1 + (k0), lA + (b) * 16384 + 8192); } while (0)
#define STAGE_B(b, k0) do {                                       \
        load_lds16(gB0 + (k0), lB + (b) * 16384);                 \
        load_lds16(gB1 + (k0), lB + (b) * 16384 + 8192); } while (0)

    // Fragment ds_read offsets: logical = row*64 + quad*16 bytes,
    // phys = logical ^ (((row>>1)&3)<<4); row bits 1-2 come from l16.
    const int fsw  = ((l16 >> 1) & 3) << 4;
    const int offA = (((wr * 128 + l16) * 64 + quad * 16) ^ fsw);
    const int offB = (((wc * 64  + l16) * 64 + quad * 16) ^ fsw);

    bf16x8 aF[4], bF[4];

#define READ_A(bufoff, mb) do { _Pragma("unroll")                              \
        for (int mi = 0; mi < 4; ++mi)                                         \
            aF[mi] = *(const bf16x8*)((const char*)sA + (bufoff) + offA +      \
                                      ((mb) + mi) * 1024); } while (0)
#define READ_B(bufoff) do { _Pragma("unroll")                                  \
        for (int ni = 0; ni < 4; ++ni)                                         \
            bF[ni] = *(const bf16x8*)((const char*)sB + (bufoff) + offB +      \
                                      ni * 1024); } while (0)
#define MFMA_Q(mb) do { _Pragma("unroll")                                      \
        for (int mi = 0; mi < 4; ++mi) { _Pragma("unroll")                     \
            for (int ni = 0; ni < 4; ++ni)                                     \
                acc[(mb) + mi][ni] = __builtin_amdgcn_mfma_f32_16x16x32_bf16(  \
                    aF[mi], bF[ni], acc[(mb) + mi][ni], 0, 0, 0); } } while (0)

#define BAR()   __builtin_amdgcn_s_barrier()
#define FENCE() asm volatile("" ::: "memory")

    // Prologue: tiles 0..2 issued (12 loads/wave); vmcnt(8) => tile 0 landed.
    STAGE_A(0, 0);  STAGE_B(0, 0);
    STAGE_A(1, 32); STAGE_B(1, 32);
    STAGE_A(2, 64); STAGE_B(2, 64);
    asm volatile("s_waitcnt vmcnt(8)" ::: "memory");
    BAR(); FENCE();

    for (int tt = 0; tt < NT - 3; ++tt) {
        const int bufoff = (tt & 3) * 16384;
        const int nb     = (tt + 3) & 3;   // buffer freed at end of tile tt-1
        const int k0n    = (tt + 3) * 32;
        // ---- phase 0: quadrant mi 0-3 (stage next A in parallel)
        STAGE_A(nb, k0n);
        READ_A(bufoff, 0);
        READ_B(bufoff);
        BAR(); FENCE();
        __builtin_amdgcn_s_setprio(1);
        MFMA_Q(0);
        __builtin_amdgcn_s_setprio(0);
        BAR(); FENCE();
        // ---- phase 1: quadrant mi 4-7 (stage next B; bF reused)
        STAGE_B(nb, k0n);
        READ_A(bufoff, 4);
        BAR(); FENCE();
        __builtin_amdgcn_s_setprio(1);
        MFMA_Q(4);
        __builtin_amdgcn_s_setprio(0);
        // issued = 12 + 4(tt+1); need tiles <= tt+1 landed => 8 outstanding
        asm volatile("s_waitcnt vmcnt(8)" ::: "memory");
        BAR(); FENCE();
    }

#define TAIL_TILE(tt, WAITER) do {                                             \
        const int bufoff = ((tt) & 3) * 16384;                                 \
        READ_A(bufoff, 0); READ_B(bufoff);                                     \
        BAR(); FENCE();                                                        \
        __builtin_amdgcn_s_setprio(1); MFMA_Q(0); __builtin_amdgcn_s_setprio(0); \
        BAR(); FENCE();                                                        \
        READ_A(bufoff, 4);                                                     \
        BAR(); FENCE();                                                        \
        __builtin_amdgcn_s_setprio(1); MFMA_Q(4); __builtin_amdgcn_s_setprio(0); \
        WAITER;                                                                \
        BAR(); FENCE(); } while (0)

    TAIL_TILE(NT - 3, asm volatile("s_waitcnt vmcnt(4)" ::: "memory"));
    TAIL_TILE(NT - 2, asm volatile("s_waitcnt vmcnt(0)" ::: "memory"));
    TAIL_TILE(NT - 1, );

    // Epilogue: C/D layout col = lane&15, row = quad*4 + reg (m89/m91-verified)
#pragma unroll
    for (int mi = 0; mi < 8; ++mi) {
#pragma unroll
        for (int ni = 0; ni < 4; ++ni) {
            const int col  = tileN + wc * 64 + ni * 16 + l16;
            const int rowb = tileM + wr * 128 + mi * 16 + quad * 4;
#pragma unroll
            for (int r = 0; r < 4; ++r) {
                const size_t idx = (size_t)(rowb + r) * HD + col;
                C[idx] = acc[mi][ni][r] * alpha + C[idx];
            }
        }
    }
}

// ---------------------------------------------------------------------------
extern "C" void kernel_launch(void* const* d_in, const int* in_sizes, int n_in,
                              void* d_out, int out_size, void* d_ws, size_t ws_size,
                              hipStream_t stream) {
    const float* hidden = (const float*)d_in[0];   // [T, H] fp32
    const float* norm_w = (const float*)d_in[1];   // [4, H]
    const float* w      = (const float*)d_in[2];   // [3, H, H]
    const float* ag     = (const float*)d_in[3];   // [3]
    const float* wg     = (const float*)d_in[4];   // [3]
    float* out = (float*)d_out;                    // reused as resid/x, then final y

    char* ws = (char*)d_ws;
    bf16* Bdeq = (bf16*)ws;                              // 3*H*H*2 = 100663296 B
    bf16* Adeq = (bf16*)(ws + (size_t)3 * HD * HD * 2);  // T*H*2   =  67108864 B

    // 1) weight quant+dequant (3*H*H/4 float4s / 256 threads)
    quant_w_kernel<<<(3 * HD * (HD / 4)) / 256, 256, 0, stream>>>(w, wg, Bdeq);

    // 2) relu + resid + rmsnorm(norm_w[0]) + quant(ag[0])
    rms_quant_kernel<<<TD, 256, 0, stream>>>(hidden, out, norm_w, ag, Adeq, nullptr, 0);

    // 3) three fused-FP4 GEMM layers (256x256 tiles: 32 x 16 = 512 blocks)
    for (int i = 0; i < 3; i++) {
        gemm_bt_kernel<<<512, 512, 0, stream>>>(
            Adeq, Bdeq + (size_t)i * HD * HD, out, ag + i, wg + i);
        if (i < 2) {
            rms_quant_kernel<<<TD, 256, 0, stream>>>(
                out, nullptr, norm_w + (size_t)(i + 1) * HD, ag + (i + 1),
                Adeq, nullptr, 1);
        } else {
            rms_quant_kernel<<<TD, 256, 0, stream>>>(
                out, nullptr, norm_w + (size_t)3 * HD, nullptr,
                nullptr, out, 2);
        }
    }
    (void)in_sizes; (void)n_in; (void)out_size; (void)ws_size;
}